// Round 16
// baseline (208.048 us; speedup 1.0000x reference)
//
#include <hip/hip_runtime.h>

// VectorQuantizer on MI355X — MFMA f16-split, z-in-regs, BARRIER-FREE per-wave
// private LDS staging, score-derived loss, separate gather kernel for z_q.
// z: [64,1024,256] f32 -> N=65536 rows, D=256. codebook: [1024,256] f32, K=1024.
// Outputs (concat flat): z_q (16777216 f32), loss (1), perplexity (1).
//
// Precision: v = hi + lo/2048 (f16 each); dot = hh + (x1 + x2)/2048.
// Round-16: each wave owns a private 16KB LDS dbuf and self-stages its B slice
// (32 codes x 64 k hi+lo = 8KB units) with per-wave counted vmcnt(8) -> ZERO
// s_barrier in the K loop; 8 waves drift and mutually hide stalls. cnorm moved
// to LDS (prologue) so folds never touch vmcnt (the old per-lane cnorm global
// gather forced compiler vmcnt drains every chunk).
// HARD-WON RULES: __launch_bounds__(512,2) ONLY; 256-thread / min-waves=3 /
// 6-acc / kh-conditional variants all spill. Spill signature = WRITE/FETCH
// balloon (rounds 7/9/12/14). zh[] indices must be compile-time (rule #20).

#define N_ROWS 65536
#define DIM    256
#define K_CODES 1024
#define BETA   0.001f

#define BM      128                // rows per block
#define NBLOCKS (N_ROWS / BM)      // 512
#define NTHREADS 512

#define LO_SCALE 2048.0f
#define LO_INV   (1.0f / 2048.0f)

// ws layout (bytes):
//   [0,4096)        cnorm (1024 f32)
//   [4096,8192)     counts (1024 int)
//   [8192,12288)    ploss (512 f32 used)
//   [16384,278528)  bests (65536 int)
//   [278528,...)    codebook f16 hi/lo image, 32 units x 32768 B = 1 MB
#define WS_BESTS_OFF 16384
#define WS_CBIMG_OFF 278528
#define WS_NEED (WS_CBIMG_OFF + 32 * 32768)

typedef _Float16 f16x8 __attribute__((ext_vector_type(8)));
typedef float f32x16 __attribute__((ext_vector_type(16)));

// ---------------- prep kernels ----------------

__global__ void cnorm_kernel(const float* __restrict__ cb, float* __restrict__ cnorm) {
    int k = blockIdx.x * blockDim.x + threadIdx.x;
    if (k >= K_CODES) return;
    const float4* row = (const float4*)(cb + (size_t)k * DIM);
    float s = 0.f;
#pragma unroll
    for (int j = 0; j < DIM / 4; ++j) {
        float4 v = row[j];
        s = fmaf(v.x, v.x, s);
        s = fmaf(v.y, v.y, s);
        s = fmaf(v.z, v.z, s);
        s = fmaf(v.w, v.w, s);
    }
    cnorm[k] = s;
}

// Codebook f32 -> f16 hi/lo(scaled), GRANULE-MAJOR image (round-12/13-proven):
// image unit iu = chunk*2 + kh (64 codes x 128 k), 32768 B each:
//   hi at byte = gl*1024 + cl*16  (gl = k-granule 0..15, cl = code 0..63)
//   lo at +16384, same layout.
__global__ void cb_prep(const float* __restrict__ cb, char* __restrict__ img) {
    int idx = blockIdx.x * blockDim.x + threadIdx.x;   // 0..32767
    int c   = idx >> 5;          // code 0..1023
    int g32 = idx & 31;          // granule of 8 floats over 256 dims
    const float4* src = (const float4*)(cb + (size_t)c * DIM + g32 * 8);
    float4 v0 = src[0], v1 = src[1];
    float vv[8] = {v0.x, v0.y, v0.z, v0.w, v1.x, v1.y, v1.z, v1.w};
    f16x8 hi, lo;
#pragma unroll
    for (int j = 0; j < 8; ++j) {
        _Float16 h = (_Float16)vv[j];
        hi[j] = h;
        lo[j] = (_Float16)((vv[j] - (float)h) * LO_SCALE);
    }
    int kh = g32 >> 4;           // 128-k half -> image unit
    int gl = g32 & 15;           // granule within half
    int cl = c & 63;
    int iu = (c >> 6) * 2 + kh;
    size_t off = (size_t)iu * 32768 + (size_t)gl * 1024 + (size_t)cl * 16;
    *(f16x8*)(img + off) = hi;
    *(f16x8*)(img + off + 16384) = lo;
}

// ---------------- MFMA main kernel ----------------

// Stage one per-wave 8KB unit s (= chunk*4 + q; 32 codes x 64 k, hi+lo).
// 8 gload_lds x (64 lanes x 16B). LDS dst layout: hi granule j at j*512,
// lo at 4096 + j*512 (j = 0..7 within unit). Global src: image unit
// (chunk*2 + q>>1), granules (q&1)*8 + j, code-half wc.
__device__ inline void stage_u(const char* __restrict__ img, int s, int wc,
                               int lane, char* dst) {
    int chunk = s >> 2, q = s & 3;
    const char* base = img + (size_t)(chunk * 2 + (q >> 1)) * 32768
                     + (size_t)((q & 1) * 8) * 1024 + wc * 512
                     + (lane >> 5) * 1024 + (lane & 31) * 16;
#pragma unroll
    for (int i = 0; i < 4; ++i) {
        __builtin_amdgcn_global_load_lds(
            (const __attribute__((address_space(1))) unsigned int*)(base + i * 2048),
            (__attribute__((address_space(3))) unsigned int*)(dst + i * 1024),
            16, 0, 0);
        __builtin_amdgcn_global_load_lds(
            (const __attribute__((address_space(1))) unsigned int*)(base + 16384 + i * 2048),
            (__attribute__((address_space(3))) unsigned int*)(dst + 4096 + i * 1024),
            16, 0, 0);
    }
}

// B-fragment LDS read within the wave's current 8KB buffer (f16* ub):
// bytes (R*2+lh)*512 + l31*16, lo at +4096. Wave-wide contiguous -> 0 conflicts.
#define LOADB_U(R, BH, BL)                                                           \
    {                                                                                \
        const _Float16* p = ub + ((R) * 2 + lh) * 256 + l31 * 8;                     \
        BH = *(const f16x8*)(p);                                                     \
        BL = *(const f16x8*)(p + 2048);                                              \
    }

// MFMA triple for global step KS — identical order/accumulation to round 13.
#define MF3(KS, BH, BL)                                                              \
    {                                                                                \
        f16x8 ah = zh[KS], al = zl[KS];                                              \
        acc_hh = __builtin_amdgcn_mfma_f32_32x32x16_f16(ah, BH, acc_hh, 0, 0, 0);    \
        acc_x1 = __builtin_amdgcn_mfma_f32_32x32x16_f16(ah, BL, acc_x1, 0, 0, 0);    \
        acc_x2 = __builtin_amdgcn_mfma_f32_32x32x16_f16(al, BH, acc_x2, 0, 0, 0);    \
    }

// One unit phase: per-wave vmcnt wait -> 8 ds_read -> lgkmcnt(0) ->
// stage(s+2) into this buffer -> 12 MFMA. NO barriers. Q is a literal.
#define UNIT_PHASE(CHUNK, Q, WAITN, DOSTAGE)                                         \
    {                                                                                \
        asm volatile("s_waitcnt vmcnt(" #WAITN ")" ::: "memory");                    \
        const _Float16* ub = wlds + ((Q) & 1) * 4096;                                \
        f16x8 bh0, bl0, bh1, bl1, bh2, bl2, bh3, bl3;                                \
        LOADB_U(0, bh0, bl0)                                                         \
        LOADB_U(1, bh1, bl1)                                                         \
        LOADB_U(2, bh2, bl2)                                                         \
        LOADB_U(3, bh3, bl3)                                                         \
        asm volatile("s_waitcnt lgkmcnt(0)" ::: "memory");                           \
        if (DOSTAGE)                                                                 \
            stage_u(img, (CHUNK) * 4 + (Q) + 2, wc, lane,                            \
                    (char*)wlds + ((Q) & 1) * 8192);                                 \
        __builtin_amdgcn_s_setprio(1);                                               \
        MF3((Q) * 4 + 0, bh0, bl0)                                                   \
        MF3((Q) * 4 + 1, bh1, bl1)                                                   \
        MF3((Q) * 4 + 2, bh2, bl2)                                                   \
        MF3((Q) * 4 + 3, bh3, bl3)                                                   \
        __builtin_amdgcn_s_setprio(0);                                               \
    }

#define FOLD(CHUNK)                                                                  \
    {                                                                                \
        int col = (CHUNK) * 64 + crow;                                               \
        float cn = cnorm_lds[col];                                                   \
        _Pragma("unroll")                                                            \
        for (int rg = 0; rg < 16; ++rg) {                                            \
            float dot = fmaf(acc_x1[rg] + acc_x2[rg], LO_INV, acc_hh[rg]);           \
            float s = fmaf(-2.0f, dot, cn);                                          \
            bool take = s < best_s[rg];                                              \
            best_s[rg] = take ? s : best_s[rg];                                      \
            best_c[rg] = take ? col : best_c[rg];                                    \
        }                                                                            \
        _Pragma("unroll")                                                            \
        for (int e = 0; e < 16; ++e) {                                               \
            acc_hh[e] = 0.f; acc_x1[e] = 0.f; acc_x2[e] = 0.f;                       \
        }                                                                            \
    }

__global__ __launch_bounds__(NTHREADS, 2)
void vq_main_mfma(const float* __restrict__ z, const char* __restrict__ img,
                  const float* __restrict__ cnorm, int* __restrict__ bests_g,
                  int* __restrict__ counts, float* __restrict__ ploss) {
    __shared__ _Float16 csb[8 * 8192];           // 128 KB: 16 KB private per wave
    __shared__ float cnorm_lds[1024];            // 4 KB
    __shared__ float bs2[BM][2];
    __shared__ int   bc2[BM][2];
    __shared__ float znorm_lds[BM];
    __shared__ float red[NTHREADS];

    const int tid  = threadIdx.x;
    const int lane = tid & 63;
    const int w    = tid >> 6;      // wave 0..7
    const int wr   = w >> 1;        // row-tile 0..3 (32 rows each)
    const int wc   = w & 1;         // col-half of 64-code chunk
    const int l31  = lane & 31;
    const int lh   = lane >> 5;
    const int r0   = blockIdx.x * BM;

    _Float16* wlds = csb + w * 8192;             // this wave's 16 KB (f16 units)

    // ---- z fragments -> registers (f16 hi/lo, MFMA A layout) + row norms ----
    const int zrow = wr * 32 + l31;
    f16x8 zh[16], zl[16];
    {
        const float* zr = z + (size_t)(r0 + zrow) * DIM;
        float zn = 0.f;
#pragma unroll
        for (int gi = 0; gi < 16; ++gi) {
            int g = gi * 2 + lh;                 // granule parity = lh
            float4 v0 = *(const float4*)(zr + g * 8);
            float4 v1 = *(const float4*)(zr + g * 8 + 4);
            float vv[8] = {v0.x, v0.y, v0.z, v0.w, v1.x, v1.y, v1.z, v1.w};
            f16x8 hi, lo;
#pragma unroll
            for (int j = 0; j < 8; ++j) {
                _Float16 h = (_Float16)vv[j];
                hi[j] = h;
                lo[j] = (_Float16)((vv[j] - (float)h) * LO_SCALE);
                zn = fmaf(vv[j], vv[j], zn);
            }
            zh[gi] = hi;
            zl[gi] = lo;
        }
        zn += __shfl_xor(zn, 32, 64);            // combine lh halves
        if (wc == 0 && lh == 0) znorm_lds[zrow] = zn;
    }

    // ---- cnorm -> LDS (folds must not touch vmcnt) ----
    cnorm_lds[tid]       = cnorm[tid];
    cnorm_lds[tid + 512] = cnorm[tid + 512];
    __syncthreads();                             // the ONLY pre-epilogue barrier

    // ---- prologue staging: units 0 and 1 (16 vmcnt outstanding) ----
    stage_u(img, 0, wc, lane, (char*)wlds);
    stage_u(img, 1, wc, lane, (char*)wlds + 8192);

    f32x16 acc_hh, acc_x1, acc_x2;
#pragma unroll
    for (int e = 0; e < 16; ++e) { acc_hh[e] = 0.f; acc_x1[e] = 0.f; acc_x2[e] = 0.f; }
    float best_s[16];
    int   best_c[16];
#pragma unroll
    for (int e = 0; e < 16; ++e) { best_s[e] = 3.4e38f; best_c[e] = 0; }

    const int crow = wc * 32 + l31;              // code row within 64-chunk

#pragma unroll 1
    for (int chunk = 0; chunk < 15; ++chunk) {
        UNIT_PHASE(chunk, 0, 8, 1)
        UNIT_PHASE(chunk, 1, 8, 1)
        UNIT_PHASE(chunk, 2, 8, 1)
        UNIT_PHASE(chunk, 3, 8, 1)
        FOLD(chunk)
    }
    // peeled last chunk: stop staging at s=61 (stage(63)), drain tail.
    UNIT_PHASE(15, 0, 8, 1)
    UNIT_PHASE(15, 1, 8, 1)
    UNIT_PHASE(15, 2, 8, 0)
    UNIT_PHASE(15, 3, 0, 0)
    FOLD(15)

    // ---- reduce best over the 32 lanes of each half (codes axis) ----
#pragma unroll
    for (int rg = 0; rg < 16; ++rg) {
        float bsv = best_s[rg];
        int   bcv = best_c[rg];
#pragma unroll
        for (int s = 1; s < 32; s <<= 1) {
            float os = __shfl_xor(bsv, s, 64);
            int   oc = __shfl_xor(bcv, s, 64);
            bool take = (os < bsv) || (os == bsv && oc < bcv);
            bsv = take ? os : bsv;
            bcv = take ? oc : bcv;
        }
        best_s[rg] = bsv;
        best_c[rg] = bcv;
    }
    if (l31 == 0) {
#pragma unroll
        for (int rg = 0; rg < 16; ++rg) {
            int rl = (rg & 3) + 8 * (rg >> 2) + 4 * lh;   // C/D row mapping (m74/m101)
            bs2[wr * 32 + rl][wc] = best_s[rg];
            bc2[wr * 32 + rl][wc] = best_c[rg];
        }
    }
    __syncthreads();

    // ---- combine wc halves, emit bests + per-row loss (score + ||z||^2) ----
    float lsum = 0.f;
    if (tid < BM) {
        float s0 = bs2[tid][0], s1 = bs2[tid][1];
        int   c0 = bc2[tid][0], c1 = bc2[tid][1];
        bool t1 = (s1 < s0) || (s1 == s0 && c1 < c0);
        int   bc = t1 ? c1 : c0;
        float bs = t1 ? s1 : s0;
        bests_g[r0 + tid] = bc;
        atomicAdd(&counts[bc], 1);
        lsum = bs + znorm_lds[tid];              // ||z - c||^2
    }
    red[tid] = lsum;
    __syncthreads();
    for (int s = NTHREADS / 2; s > 0; s >>= 1) {
        if (tid < s) red[tid] += red[tid + s];
        __syncthreads();
    }
    if (tid == 0) ploss[blockIdx.x] = red[0];
}

// ---------------- z_q gather kernel (z + stopgrad(zq - z) == codebook row) ----

__global__ __launch_bounds__(256)
void vq_gather(const float4* __restrict__ cb4, const int* __restrict__ bests,
               float4* __restrict__ out4) {
    int gid = blockIdx.x * blockDim.x + threadIdx.x;   // 0 .. 4194303
    int row = gid >> 6;
    int q   = gid & 63;
    out4[gid] = cb4[(size_t)bests[row] * 64 + q];
}

// ---------------- fallback fp32 kernel (round-1, known-good) ----------------

#define FBM     32
#define FCHUNK  512
#define FDSTAGE 16
#define FCS_PAD 20
#define FNBLOCKS (N_ROWS / FBM)   // 2048

__global__ __launch_bounds__(256, 2)
void vq_main_fp32(const float* __restrict__ z, const float* __restrict__ cb,
                  const float* __restrict__ cnorm, float* __restrict__ out,
                  int* __restrict__ counts, float* __restrict__ ploss) {
    __shared__ float zs[FBM][DIM];
    __shared__ float cs[FCHUNK][FCS_PAD];
    __shared__ int   bests[FBM];
    __shared__ float red[256];

    const int tid = threadIdx.x;
    const int tx  = tid & 63;
    const int ty  = tid >> 6;
    const int r0  = blockIdx.x * FBM;

    {
        const float4* zg  = (const float4*)(z + (size_t)r0 * DIM);
        float4*       zsv = (float4*)&zs[0][0];
#pragma unroll
        for (int j = 0; j < (FBM * DIM / 4) / 256; ++j)
            zsv[tid + 256 * j] = zg[tid + 256 * j];
    }

    unsigned long long best[8];
#pragma unroll
    for (int i = 0; i < 8; ++i) best[i] = ~0ull;

    for (int cb0 = 0; cb0 < K_CODES; cb0 += FCHUNK) {
        float acc[8][8];
#pragma unroll
        for (int i = 0; i < 8; ++i)
#pragma unroll
            for (int m = 0; m < 8; ++m) acc[i][m] = 0.f;

        for (int sd = 0; sd < DIM / FDSTAGE; ++sd) {
            __syncthreads();
#pragma unroll
            for (int j = 0; j < 8; ++j) {
                int f4i = tid + 256 * j;
                int c   = f4i >> 2;
                int qq  = f4i & 3;
                float4 v = *(const float4*)(cb + (size_t)(cb0 + c) * DIM + sd * FDSTAGE + qq * 4);
                *(float4*)&cs[c][qq * 4] = v;
            }
            __syncthreads();

#pragma unroll
            for (int dd4 = 0; dd4 < FDSTAGE / 4; ++dd4) {
                float4 zv[8], cv[8];
#pragma unroll
                for (int i = 0; i < 8; ++i)
                    zv[i] = *(const float4*)&zs[ty * 8 + i][sd * FDSTAGE + dd4 * 4];
#pragma unroll
                for (int m = 0; m < 8; ++m)
                    cv[m] = *(const float4*)&cs[tx + 64 * m][dd4 * 4];
#pragma unroll
                for (int i = 0; i < 8; ++i)
#pragma unroll
                    for (int m = 0; m < 8; ++m) {
                        float a = acc[i][m];
                        a = fmaf(zv[i].x, cv[m].x, a);
                        a = fmaf(zv[i].y, cv[m].y, a);
                        a = fmaf(zv[i].z, cv[m].z, a);
                        a = fmaf(zv[i].w, cv[m].w, a);
                        acc[i][m] = a;
                    }
            }
        }

#pragma unroll
        for (int m = 0; m < 8; ++m) {
            int   c  = cb0 + tx + 64 * m;
            float cn = cnorm[c];
#pragma unroll
            for (int i = 0; i < 8; ++i) {
                float s = fmaf(-2.f, acc[i][m], cn);
                unsigned u = __float_as_uint(s);
                u = (u & 0x80000000u) ? ~u : (u | 0x80000000u);
                unsigned long long key = ((unsigned long long)u << 32) | (unsigned)c;
                best[i] = key < best[i] ? key : best[i];
            }
        }
    }

#pragma unroll
    for (int i = 0; i < 8; ++i) {
        unsigned long long b = best[i];
#pragma unroll
        for (int s = 1; s < 64; s <<= 1) {
            unsigned long long o = __shfl_xor(b, s, 64);
            b = o < b ? o : b;
        }
        best[i] = b;
    }
    if (tx == 0)
#pragma unroll
        for (int i = 0; i < 8; ++i)
            bests[ty * 8 + i] = (int)(best[i] & 0xFFFFFFFFu);
    __syncthreads();

    const int r  = tid >> 3;
    const int lq = tid & 7;
    const int bidx = bests[r];
    const float4* crow = (const float4*)(cb + (size_t)bidx * DIM);
    const float4* zrow = (const float4*)&zs[r][0];
    float4*       orow = (float4*)(out + (size_t)(r0 + r) * DIM);
    float lsum = 0.f;
#pragma unroll
    for (int j = 0; j < 8; ++j) {
        int qg = lq + j * 8;
        float4 c4 = crow[qg];
        float4 z4 = zrow[qg];
        float4 o;
        float dx = c4.x - z4.x; o.x = z4.x + dx; lsum = fmaf(dx, dx, lsum);
        float dy = c4.y - z4.y; o.y = z4.y + dy; lsum = fmaf(dy, dy, lsum);
        float dz = c4.z - z4.z; o.z = z4.z + dz; lsum = fmaf(dz, dz, lsum);
        float dw = c4.w - z4.w; o.w = z4.w + dw; lsum = fmaf(dw, dw, lsum);
        orow[qg] = o;
    }
    if (tid < FBM) atomicAdd(&counts[bests[tid]], 1);

    red[tid] = lsum;
    __syncthreads();
    for (int s = 128; s > 0; s >>= 1) {
        if (tid < s) red[tid] += red[tid + s];
        __syncthreads();
    }
    if (tid == 0) ploss[blockIdx.x] = red[0];
}

// ---------------- finalize ----------------

__global__ void vq_final(const float* __restrict__ ploss, const int* __restrict__ counts,
                         const int* __restrict__ flg, float* __restrict__ out2, int np) {
    __shared__ float red[1024];
    const int t = threadIdx.x;

    float l = 0.f;
    for (int i = t; i < np; i += 1024) l += ploss[i];
    red[t] = l;
    __syncthreads();
    for (int s = 512; s > 0; s >>= 1) {
        if (t < s) red[t] += red[t + s];
        __syncthreads();
    }
    if (t == 0) {
        float loss = (red[0] / (float)((size_t)N_ROWS * DIM)) * (1.0f + BETA);
        if (flg[0] == 0) loss = 0.f;
        out2[0] = loss;
    }
    __syncthreads();

    float e = (float)counts[t] / (float)N_ROWS;
    red[t] = e * logf(e + 1e-10f);
    __syncthreads();
    for (int s = 512; s > 0; s >>= 1) {
        if (t < s) red[t] += red[t + s];
        __syncthreads();
    }
    if (t == 0) out2[1] = expf(-red[0]);
}

extern "C" void kernel_launch(void* const* d_in, const int* in_sizes, int n_in,
                              void* d_out, int out_size, void* d_ws, size_t ws_size,
                              hipStream_t stream) {
    const float* z   = (const float*)d_in[0];
    const float* cb  = (const float*)d_in[1];
    const int*   flg = (const int*)d_in[2];
    float* out = (float*)d_out;
    float* ws  = (float*)d_ws;

    float* cnorm  = ws;
    int*   counts = (int*)((char*)d_ws + 4096);
    float* ploss  = (float*)((char*)d_ws + 8192);
    int*   bests  = (int*)((char*)d_ws + WS_BESTS_OFF);
    char*  cbimg  = (char*)d_ws + WS_CBIMG_OFF;

    hipMemsetAsync(counts, 0, K_CODES * sizeof(int), stream);
    cnorm_kernel<<<K_CODES / 256, 256, 0, stream>>>(cb, cnorm);

    if (ws_size >= (size_t)WS_NEED) {
        cb_prep<<<128, 256, 0, stream>>>(cb, cbimg);
        vq_main_mfma<<<NBLOCKS, NTHREADS, 0, stream>>>(z, cbimg, cnorm, bests, counts, ploss);
        vq_gather<<<(N_ROWS * 64) / 256, 256, 0, stream>>>((const float4*)cb, bests, (float4*)out);
        vq_final<<<1, 1024, 0, stream>>>(ploss, counts, flg, out + (size_t)N_ROWS * DIM, NBLOCKS);
    } else {
        vq_main_fp32<<<FNBLOCKS, 256, 0, stream>>>(z, cb, cnorm, out, counts, ploss);
        vq_final<<<1, 1024, 0, stream>>>(ploss, counts, flg, out + (size_t)N_ROWS * DIM, FNBLOCKS);
    }
}

// Round 17
// 174.076 us; speedup vs baseline: 1.1952x; 1.1952x over previous
//
#include <hip/hip_runtime.h>

// VectorQuantizer on MI355X — MFMA f16-split, z-in-regs, SINGLE-buffer chunk
// staging at 2 blocks/CU, score-derived loss, separate gather kernel for z_q.
// z: [64,1024,256] f32 -> N=65536 rows, D=256. codebook: [1024,256] f32, K=1024.
// Outputs (concat flat): z_q (16777216 f32), loss (1), perplexity (1).
//
// Precision: v = hi + lo/2048 (f16 each); dot = hh + (x1 + x2)/2048.
// Round-17 = round-13 compute (granule-major 0-conflict image, 3 acc chains)
// with the 128KB double-buffer replaced by a SINGLE 64KB buffer -> ~74KB LDS
// -> TWO blocks resident per CU (grid 512 = 2x256). The exposed per-chunk
// stage latency is covered by the other block's compute phase (m114 implicit
// overlap — the mechanism all 1-block/CU dbuf variants lacked). Fold issues
// after stage(c+1) so its VALU also hides under the stage.
// HARD-WON RULES: __launch_bounds__(512,2) ONLY; 256-thread / min-waves=3 /
// 6-acc / kh-conditional / per-wave-private variants all spill. Spill
// signature = WRITE/FETCH balloon (rounds 7/9/12/14/16).

#define N_ROWS 65536
#define DIM    256
#define K_CODES 1024
#define BETA   0.001f

#define BM      128                // rows per block
#define NBLOCKS (N_ROWS / BM)      // 512 = 2 x 256 CUs, both resident
#define NTHREADS 512
#define CHUNK_BYTES 65536          // 64 codes x 256 k x (hi+lo) x 2B
#define NCHUNK  16

#define LO_SCALE 2048.0f
#define LO_INV   (1.0f / 2048.0f)

// ws layout (bytes):
//   [0,4096)        cnorm (1024 f32)
//   [4096,8192)     counts (1024 int)
//   [8192,12288)    ploss (512 f32 used)
//   [16384,278528)  bests (65536 int)
//   [278528,...)    codebook f16 hi/lo image, 16 chunks x 65536 B = 1 MB
#define WS_BESTS_OFF 16384
#define WS_CBIMG_OFF 278528
#define WS_NEED (WS_CBIMG_OFF + NCHUNK * CHUNK_BYTES)

typedef _Float16 f16x8 __attribute__((ext_vector_type(8)));
typedef float f32x16 __attribute__((ext_vector_type(16)));

// ---------------- prep kernels ----------------

__global__ void cnorm_kernel(const float* __restrict__ cb, float* __restrict__ cnorm) {
    int k = blockIdx.x * blockDim.x + threadIdx.x;
    if (k >= K_CODES) return;
    const float4* row = (const float4*)(cb + (size_t)k * DIM);
    float s = 0.f;
#pragma unroll
    for (int j = 0; j < DIM / 4; ++j) {
        float4 v = row[j];
        s = fmaf(v.x, v.x, s);
        s = fmaf(v.y, v.y, s);
        s = fmaf(v.z, v.z, s);
        s = fmaf(v.w, v.w, s);
    }
    cnorm[k] = s;
}

// Codebook f32 -> f16 hi/lo(scaled), GRANULE-MAJOR image (round-12/13-proven):
// unit u = chunk*2 + kh (64 codes x 128 k), 32768 B each:
//   hi at byte = gl*1024 + cl*16  (gl = k-granule 0..15, cl = code 0..63)
//   lo at +16384, same layout. Chunk c occupies [c*65536, (c+1)*65536).
__global__ void cb_prep(const float* __restrict__ cb, char* __restrict__ img) {
    int idx = blockIdx.x * blockDim.x + threadIdx.x;   // 0..32767
    int c   = idx >> 5;          // code 0..1023
    int g32 = idx & 31;          // granule of 8 floats over 256 dims
    const float4* src = (const float4*)(cb + (size_t)c * DIM + g32 * 8);
    float4 v0 = src[0], v1 = src[1];
    float vv[8] = {v0.x, v0.y, v0.z, v0.w, v1.x, v1.y, v1.z, v1.w};
    f16x8 hi, lo;
#pragma unroll
    for (int j = 0; j < 8; ++j) {
        _Float16 h = (_Float16)vv[j];
        hi[j] = h;
        lo[j] = (_Float16)((vv[j] - (float)h) * LO_SCALE);
    }
    int kh = g32 >> 4;           // 128-k half -> unit
    int gl = g32 & 15;           // granule within half
    int cl = c & 63;
    int unit = (c >> 6) * 2 + kh;
    size_t off = (size_t)unit * 32768 + (size_t)gl * 1024 + (size_t)cl * 16;
    *(f16x8*)(img + off) = hi;
    *(f16x8*)(img + off + 16384) = lo;
}

// ---------------- MFMA main kernel ----------------

__device__ inline void stage_chunk(const char* img, int c, char* ldsbase, int tid) {
#pragma unroll
    for (int i = 0; i < 8; ++i) {
        __builtin_amdgcn_global_load_lds(
            (const __attribute__((address_space(1))) unsigned int*)
                (img + (size_t)c * CHUNK_BYTES + i * 8192 + tid * 16),
            (__attribute__((address_space(3))) unsigned int*)
                (ldsbase + i * 8192 + tid * 16),
            16, 0, 0);
    }
}

// Full chunk (16 ks steps), 3 accumulator chains (reuse distance 3 MFMAs).
// Granule-major f16 offsets: half (ks>>3)*16384, granule ((ks&7)*2+lh)*512,
// code crow*8. Wave-wide contiguous reads -> 0 bank conflicts.
#define COMPUTE_CHUNK()                                                              \
    {                                                                                \
        const _Float16* bbase = csb + crow * 8;                                      \
        _Pragma("unroll")                                                            \
        for (int ks = 0; ks < 16; ++ks) {                                            \
            const _Float16* p = bbase + (ks >> 3) * 16384 + ((ks & 7) * 2 + lh) * 512;\
            f16x8 bh = *(const f16x8*)(p);                                           \
            f16x8 bl = *(const f16x8*)(p + 8192);                                    \
            f16x8 ah = zh[ks], al = zl[ks];                                          \
            acc_hh = __builtin_amdgcn_mfma_f32_32x32x16_f16(ah, bh, acc_hh, 0, 0, 0);\
            acc_x1 = __builtin_amdgcn_mfma_f32_32x32x16_f16(ah, bl, acc_x1, 0, 0, 0);\
            acc_x2 = __builtin_amdgcn_mfma_f32_32x32x16_f16(al, bh, acc_x2, 0, 0, 0);\
        }                                                                            \
    }

__global__ __launch_bounds__(NTHREADS, 2)
void vq_main_mfma(const float* __restrict__ z, const char* __restrict__ img,
                  const float* __restrict__ cnorm, int* __restrict__ bests_g,
                  int* __restrict__ counts, float* __restrict__ ploss) {
    __shared__ _Float16 csb[32768];              // 64 KB SINGLE chunk buffer
    __shared__ float cnorm_lds[1024];            // 4 KB (folds never touch vmcnt)
    __shared__ float bs2[BM][2];
    __shared__ int   bc2[BM][2];
    __shared__ float znorm_lds[BM];
    __shared__ float red[NTHREADS];

    const int tid  = threadIdx.x;
    const int lane = tid & 63;
    const int w    = tid >> 6;      // wave 0..7
    const int wr   = w >> 1;        // row-tile 0..3 (32 rows each)
    const int wc   = w & 1;         // col-half of 64-code chunk
    const int l31  = lane & 31;
    const int lh   = lane >> 5;
    const int r0   = blockIdx.x * BM;

    // issue chunk-0 stage early (latency hides under z prologue)
    stage_chunk(img, 0, (char*)csb, tid);

    // ---- z fragments -> registers (f16 hi/lo, MFMA A layout) + row norms ----
    const int zrow = wr * 32 + l31;
    f16x8 zh[16], zl[16];
    {
        const float* zr = z + (size_t)(r0 + zrow) * DIM;
        float zn = 0.f;
#pragma unroll
        for (int gi = 0; gi < 16; ++gi) {
            int g = gi * 2 + lh;                 // granule parity = lh
            float4 v0 = *(const float4*)(zr + g * 8);
            float4 v1 = *(const float4*)(zr + g * 8 + 4);
            float vv[8] = {v0.x, v0.y, v0.z, v0.w, v1.x, v1.y, v1.z, v1.w};
            f16x8 hi, lo;
#pragma unroll
            for (int j = 0; j < 8; ++j) {
                _Float16 h = (_Float16)vv[j];
                hi[j] = h;
                lo[j] = (_Float16)((vv[j] - (float)h) * LO_SCALE);
                zn = fmaf(vv[j], vv[j], zn);
            }
            zh[gi] = hi;
            zl[gi] = lo;
        }
        zn += __shfl_xor(zn, 32, 64);            // combine lh halves
        if (wc == 0 && lh == 0) znorm_lds[zrow] = zn;
    }

    // cnorm -> LDS
    cnorm_lds[tid]       = cnorm[tid];
    cnorm_lds[tid + 512] = cnorm[tid + 512];

    f32x16 acc_hh, acc_x1, acc_x2;
#pragma unroll
    for (int e = 0; e < 16; ++e) { acc_hh[e] = 0.f; acc_x1[e] = 0.f; acc_x2[e] = 0.f; }
    float best_s[16];
    int   best_c[16];
#pragma unroll
    for (int e = 0; e < 16; ++e) { best_s[e] = 3.4e38f; best_c[e] = 0; }

    const int crow = wc * 32 + l31;              // code row within 64-chunk

#pragma unroll 1
    for (int c = 0; c < NCHUNK; ++c) {
        // stage(c) was issued last iteration (or prologue): drain own loads,
        // then barrier -> every wave's stage writes are visible.
        asm volatile("s_waitcnt vmcnt(0)" ::: "memory");
        __builtin_amdgcn_s_barrier();
        asm volatile("" ::: "memory");

        __builtin_amdgcn_s_setprio(1);
        COMPUTE_CHUNK()
        __builtin_amdgcn_s_setprio(0);

        asm volatile("" ::: "memory");
        __builtin_amdgcn_s_barrier();            // all waves done reading csb
        asm volatile("" ::: "memory");

        // refill for chunk c+1 (latency covered by fold + the other block)
        if (c + 1 < NCHUNK)
            stage_chunk(img, c + 1, (char*)csb, tid);

        // ---- fold chunk c (registers + cnorm_lds only) ----
        {
            int col = c * 64 + crow;
            float cn = cnorm_lds[col];
#pragma unroll
            for (int rg = 0; rg < 16; ++rg) {
                float dot = fmaf(acc_x1[rg] + acc_x2[rg], LO_INV, acc_hh[rg]);
                float s = fmaf(-2.0f, dot, cn);
                bool take = s < best_s[rg];      // strict: earlier (smaller) col wins ties
                best_s[rg] = take ? s : best_s[rg];
                best_c[rg] = take ? col : best_c[rg];
            }
#pragma unroll
            for (int e = 0; e < 16; ++e) { acc_hh[e] = 0.f; acc_x1[e] = 0.f; acc_x2[e] = 0.f; }
        }
    }

    // ---- reduce best over the 32 lanes of each half (codes axis) ----
#pragma unroll
    for (int rg = 0; rg < 16; ++rg) {
        float bsv = best_s[rg];
        int   bcv = best_c[rg];
#pragma unroll
        for (int s = 1; s < 32; s <<= 1) {
            float os = __shfl_xor(bsv, s, 64);
            int   oc = __shfl_xor(bcv, s, 64);
            bool take = (os < bsv) || (os == bsv && oc < bcv);
            bsv = take ? os : bsv;
            bcv = take ? oc : bcv;
        }
        best_s[rg] = bsv;
        best_c[rg] = bcv;
    }
    if (l31 == 0) {
#pragma unroll
        for (int rg = 0; rg < 16; ++rg) {
            int rl = (rg & 3) + 8 * (rg >> 2) + 4 * lh;   // C/D row mapping (m74/m101)
            bs2[wr * 32 + rl][wc] = best_s[rg];
            bc2[wr * 32 + rl][wc] = best_c[rg];
        }
    }
    __syncthreads();

    // ---- combine wc halves, emit bests + per-row loss (score + ||z||^2) ----
    float lsum = 0.f;
    if (tid < BM) {
        float s0 = bs2[tid][0], s1 = bs2[tid][1];
        int   c0 = bc2[tid][0], c1 = bc2[tid][1];
        bool t1 = (s1 < s0) || (s1 == s0 && c1 < c0);
        int   bc = t1 ? c1 : c0;
        float bs = t1 ? s1 : s0;
        bests_g[r0 + tid] = bc;
        atomicAdd(&counts[bc], 1);
        lsum = bs + znorm_lds[tid];              // ||z - c||^2
    }
    red[tid] = lsum;
    __syncthreads();
    for (int s = NTHREADS / 2; s > 0; s >>= 1) {
        if (tid < s) red[tid] += red[tid + s];
        __syncthreads();
    }
    if (tid == 0) ploss[blockIdx.x] = red[0];
}

// ---------------- z_q gather kernel (z + stopgrad(zq - z) == codebook row) ----

__global__ __launch_bounds__(256)
void vq_gather(const float4* __restrict__ cb4, const int* __restrict__ bests,
               float4* __restrict__ out4) {
    int gid = blockIdx.x * blockDim.x + threadIdx.x;   // 0 .. 4194303
    int row = gid >> 6;
    int q   = gid & 63;
    out4[gid] = cb4[(size_t)bests[row] * 64 + q];
}

// ---------------- fallback fp32 kernel (round-1, known-good) ----------------

#define FBM     32
#define FCHUNK  512
#define FDSTAGE 16
#define FCS_PAD 20
#define FNBLOCKS (N_ROWS / FBM)   // 2048

__global__ __launch_bounds__(256, 2)
void vq_main_fp32(const float* __restrict__ z, const float* __restrict__ cb,
                  const float* __restrict__ cnorm, float* __restrict__ out,
                  int* __restrict__ counts, float* __restrict__ ploss) {
    __shared__ float zs[FBM][DIM];
    __shared__ float cs[FCHUNK][FCS_PAD];
    __shared__ int   bests[FBM];
    __shared__ float red[256];

    const int tid = threadIdx.x;
    const int tx  = tid & 63;
    const int ty  = tid >> 6;
    const int r0  = blockIdx.x * FBM;

    {
        const float4* zg  = (const float4*)(z + (size_t)r0 * DIM);
        float4*       zsv = (float4*)&zs[0][0];
#pragma unroll
        for (int j = 0; j < (FBM * DIM / 4) / 256; ++j)
            zsv[tid + 256 * j] = zg[tid + 256 * j];
    }

    unsigned long long best[8];
#pragma unroll
    for (int i = 0; i < 8; ++i) best[i] = ~0ull;

    for (int cb0 = 0; cb0 < K_CODES; cb0 += FCHUNK) {
        float acc[8][8];
#pragma unroll
        for (int i = 0; i < 8; ++i)
#pragma unroll
            for (int m = 0; m < 8; ++m) acc[i][m] = 0.f;

        for (int sd = 0; sd < DIM / FDSTAGE; ++sd) {
            __syncthreads();
#pragma unroll
            for (int j = 0; j < 8; ++j) {
                int f4i = tid + 256 * j;
                int c   = f4i >> 2;
                int qq  = f4i & 3;
                float4 v = *(const float4*)(cb + (size_t)(cb0 + c) * DIM + sd * FDSTAGE + qq * 4);
                *(float4*)&cs[c][qq * 4] = v;
            }
            __syncthreads();

#pragma unroll
            for (int dd4 = 0; dd4 < FDSTAGE / 4; ++dd4) {
                float4 zv[8], cv[8];
#pragma unroll
                for (int i = 0; i < 8; ++i)
                    zv[i] = *(const float4*)&zs[ty * 8 + i][sd * FDSTAGE + dd4 * 4];
#pragma unroll
                for (int m = 0; m < 8; ++m)
                    cv[m] = *(const float4*)&cs[tx + 64 * m][dd4 * 4];
#pragma unroll
                for (int i = 0; i < 8; ++i)
#pragma unroll
                    for (int m = 0; m < 8; ++m) {
                        float a = acc[i][m];
                        a = fmaf(zv[i].x, cv[m].x, a);
                        a = fmaf(zv[i].y, cv[m].y, a);
                        a = fmaf(zv[i].z, cv[m].z, a);
                        a = fmaf(zv[i].w, cv[m].w, a);
                        acc[i][m] = a;
                    }
            }
        }

#pragma unroll
        for (int m = 0; m < 8; ++m) {
            int   c  = cb0 + tx + 64 * m;
            float cn = cnorm[c];
#pragma unroll
            for (int i = 0; i < 8; ++i) {
                float s = fmaf(-2.f, acc[i][m], cn);
                unsigned u = __float_as_uint(s);
                u = (u & 0x80000000u) ? ~u : (u | 0x80000000u);
                unsigned long long key = ((unsigned long long)u << 32) | (unsigned)c;
                best[i] = key < best[i] ? key : best[i];
            }
        }
    }

#pragma unroll
    for (int i = 0; i < 8; ++i) {
        unsigned long long b = best[i];
#pragma unroll
        for (int s = 1; s < 64; s <<= 1) {
            unsigned long long o = __shfl_xor(b, s, 64);
            b = o < b ? o : b;
        }
        best[i] = b;
    }
    if (tx == 0)
#pragma unroll
        for (int i = 0; i < 8; ++i)
            bests[ty * 8 + i] = (int)(best[i] & 0xFFFFFFFFu);
    __syncthreads();

    const int r  = tid >> 3;
    const int lq = tid & 7;
    const int bidx = bests[r];
    const float4* crow = (const float4*)(cb + (size_t)bidx * DIM);
    const float4* zrow = (const float4*)&zs[r][0];
    float4*       orow = (float4*)(out + (size_t)(r0 + r) * DIM);
    float lsum = 0.f;
#pragma unroll
    for (int j = 0; j < 8; ++j) {
        int qg = lq + j * 8;
        float4 c4 = crow[qg];
        float4 z4 = zrow[qg];
        float4 o;
        float dx = c4.x - z4.x; o.x = z4.x + dx; lsum = fmaf(dx, dx, lsum);
        float dy = c4.y - z4.y; o.y = z4.y + dy; lsum = fmaf(dy, dy, lsum);
        float dz = c4.z - z4.z; o.z = z4.z + dz; lsum = fmaf(dz, dz, lsum);
        float dw = c4.w - z4.w; o.w = z4.w + dw; lsum = fmaf(dw, dw, lsum);
        orow[qg] = o;
    }
    if (tid < FBM) atomicAdd(&counts[bests[tid]], 1);

    red[tid] = lsum;
    __syncthreads();
    for (int s = 128; s > 0; s >>= 1) {
        if (tid < s) red[tid] += red[tid + s];
        __syncthreads();
    }
    if (tid == 0) ploss[blockIdx.x] = red[0];
}

// ---------------- finalize ----------------

__global__ void vq_final(const float* __restrict__ ploss, const int* __restrict__ counts,
                         const int* __restrict__ flg, float* __restrict__ out2, int np) {
    __shared__ float red[1024];
    const int t = threadIdx.x;

    float l = 0.f;
    for (int i = t; i < np; i += 1024) l += ploss[i];
    red[t] = l;
    __syncthreads();
    for (int s = 512; s > 0; s >>= 1) {
        if (t < s) red[t] += red[t + s];
        __syncthreads();
    }
    if (t == 0) {
        float loss = (red[0] / (float)((size_t)N_ROWS * DIM)) * (1.0f + BETA);
        if (flg[0] == 0) loss = 0.f;
        out2[0] = loss;
    }
    __syncthreads();

    float e = (float)counts[t] / (float)N_ROWS;
    red[t] = e * logf(e + 1e-10f);
    __syncthreads();
    for (int s = 512; s > 0; s >>= 1) {
        if (t < s) red[t] += red[t + s];
        __syncthreads();
    }
    if (t == 0) out2[1] = expf(-red[0]);
}

extern "C" void kernel_launch(void* const* d_in, const int* in_sizes, int n_in,
                              void* d_out, int out_size, void* d_ws, size_t ws_size,
                              hipStream_t stream) {
    const float* z   = (const float*)d_in[0];
    const float* cb  = (const float*)d_in[1];
    const int*   flg = (const int*)d_in[2];
    float* out = (float*)d_out;
    float* ws  = (float*)d_ws;

    float* cnorm  = ws;
    int*   counts = (int*)((char*)d_ws + 4096);
    float* ploss  = (float*)((char*)d_ws + 8192);
    int*   bests  = (int*)((char*)d_ws + WS_BESTS_OFF);
    char*  cbimg  = (char*)d_ws + WS_CBIMG_OFF;

    hipMemsetAsync(counts, 0, K_CODES * sizeof(int), stream);
    cnorm_kernel<<<K_CODES / 256, 256, 0, stream>>>(cb, cnorm);

    if (ws_size >= (size_t)WS_NEED) {
        cb_prep<<<128, 256, 0, stream>>>(cb, cbimg);
        vq_main_mfma<<<NBLOCKS, NTHREADS, 0, stream>>>(z, cbimg, cnorm, bests, counts, ploss);
        vq_gather<<<(N_ROWS * 64) / 256, 256, 0, stream>>>((const float4*)cb, bests, (float4*)out);
        vq_final<<<1, 1024, 0, stream>>>(ploss, counts, flg, out + (size_t)N_ROWS * DIM, NBLOCKS);
    } else {
        vq_main_fp32<<<FNBLOCKS, 256, 0, stream>>>(z, cb, cnorm, out, counts, ploss);
        vq_final<<<1, 1024, 0, stream>>>(ploss, counts, flg, out + (size_t)N_ROWS * DIM, FNBLOCKS);
    }
}

// Round 18
// 163.793 us; speedup vs baseline: 1.2702x; 1.0628x over previous
//
#include <hip/hip_runtime.h>

// VectorQuantizer on MI355X — MFMA f16-split, z-in-regs, single-buffer chunk
// staging, score-derived loss, separate gather kernel for z_q.
// z: [64,1024,256] f32 -> N=65536 rows, D=256. codebook: [1024,256] f32, K=1024.
// Outputs (concat flat): z_q (16777216 f32), loss (1), perplexity (1).
//
// Precision: v = hi + lo/2048 (f16 each); dot = hh + (x1 + x2)/2048.
// Round-18 = round-17 main kernel UNCHANGED (158us, best) + cb_prep/cnorm
// fused into one kernel (one launch + one codebook read saved).
//
// STRUCTURAL CEILING NOTE: z-in-regs costs ~124 VGPR + 48 AGPR = ~172 unified
// regs/wave -> hard 2 waves/SIMD; one 8-wave barrier domain per CU. Serial
// pipe sum (MFMA 41us + LDS ~48us + VALU 24us + sync) ~= 150-160us = measured.
// All overlap attempts (rounds 9/10/11/14/15/16/17-occupancy) were bounded by
// this register wall. Alternatives measured worse: fp32-VALU 330us floor,
// z-in-LDS 325us, B-from-L2 222us.
// HARD-WON RULES: __launch_bounds__(512,2) ONLY; 256-thread / min-waves=3 /
// 6-acc / kh-conditional / per-wave-private variants all spill. Spill
// signature = WRITE/FETCH balloon (rounds 7/9/12/14/16).

#define N_ROWS 65536
#define DIM    256
#define K_CODES 1024
#define BETA   0.001f

#define BM      128                // rows per block
#define NBLOCKS (N_ROWS / BM)      // 512
#define NTHREADS 512
#define CHUNK_BYTES 65536          // 64 codes x 256 k x (hi+lo) x 2B
#define NCHUNK  16

#define LO_SCALE 2048.0f
#define LO_INV   (1.0f / 2048.0f)

// ws layout (bytes):
//   [0,4096)        cnorm (1024 f32)
//   [4096,8192)     counts (1024 int)
//   [8192,12288)    ploss (512 f32 used)
//   [16384,278528)  bests (65536 int)
//   [278528,...)    codebook f16 hi/lo image, 16 chunks x 65536 B = 1 MB
#define WS_BESTS_OFF 16384
#define WS_CBIMG_OFF 278528
#define WS_NEED (WS_CBIMG_OFF + NCHUNK * CHUNK_BYTES)

typedef _Float16 f16x8 __attribute__((ext_vector_type(8)));
typedef float f32x16 __attribute__((ext_vector_type(16)));

// ---------------- fused prep kernel: image + cnorm in one pass ----------------
// Codebook f32 -> f16 hi/lo(scaled), GRANULE-MAJOR image (round-12/13-proven):
// unit u = chunk*2 + kh (64 codes x 128 k), 32768 B each:
//   hi at byte = gl*1024 + cl*16  (gl = k-granule 0..15, cl = code 0..63)
//   lo at +16384. Chunk c occupies [c*65536, (c+1)*65536).
// cnorm[c] = ||codebook[c]||^2 via 32-lane shfl reduce (threads c*32..c*32+31
// are lanes 0-31 or 32-63 of one wave -> xor masks 1..16 stay in-group).
__global__ void cb_prep(const float* __restrict__ cb, char* __restrict__ img,
                        float* __restrict__ cnorm) {
    int idx = blockIdx.x * blockDim.x + threadIdx.x;   // 0..32767
    int c   = idx >> 5;          // code 0..1023
    int g32 = idx & 31;          // granule of 8 floats over 256 dims
    const float4* src = (const float4*)(cb + (size_t)c * DIM + g32 * 8);
    float4 v0 = src[0], v1 = src[1];
    float vv[8] = {v0.x, v0.y, v0.z, v0.w, v1.x, v1.y, v1.z, v1.w};
    f16x8 hi, lo;
    float zn = 0.f;
#pragma unroll
    for (int j = 0; j < 8; ++j) {
        _Float16 h = (_Float16)vv[j];
        hi[j] = h;
        lo[j] = (_Float16)((vv[j] - (float)h) * LO_SCALE);
        zn = fmaf(vv[j], vv[j], zn);
    }
    int kh = g32 >> 4;           // 128-k half -> unit
    int gl = g32 & 15;           // granule within half
    int cl = c & 63;
    int unit = (c >> 6) * 2 + kh;
    size_t off = (size_t)unit * 32768 + (size_t)gl * 1024 + (size_t)cl * 16;
    *(f16x8*)(img + off) = hi;
    *(f16x8*)(img + off + 16384) = lo;

    // 32-lane norm reduce (threads of one code are one aligned 32-lane group)
#pragma unroll
    for (int s = 1; s < 32; s <<= 1) zn += __shfl_xor(zn, s, 64);
    if (g32 == 0) cnorm[c] = zn;
}

// ---------------- MFMA main kernel (round-17, unchanged) ----------------

__device__ inline void stage_chunk(const char* img, int c, char* ldsbase, int tid) {
#pragma unroll
    for (int i = 0; i < 8; ++i) {
        __builtin_amdgcn_global_load_lds(
            (const __attribute__((address_space(1))) unsigned int*)
                (img + (size_t)c * CHUNK_BYTES + i * 8192 + tid * 16),
            (__attribute__((address_space(3))) unsigned int*)
                (ldsbase + i * 8192 + tid * 16),
            16, 0, 0);
    }
}

// Full chunk (16 ks steps), 3 accumulator chains (reuse distance 3 MFMAs).
// Granule-major f16 offsets: half (ks>>3)*16384, granule ((ks&7)*2+lh)*512,
// code crow*8. Wave-wide contiguous reads -> 0 bank conflicts.
#define COMPUTE_CHUNK()                                                              \
    {                                                                                \
        const _Float16* bbase = csb + crow * 8;                                      \
        _Pragma("unroll")                                                            \
        for (int ks = 0; ks < 16; ++ks) {                                            \
            const _Float16* p = bbase + (ks >> 3) * 16384 + ((ks & 7) * 2 + lh) * 512;\
            f16x8 bh = *(const f16x8*)(p);                                           \
            f16x8 bl = *(const f16x8*)(p + 8192);                                    \
            f16x8 ah = zh[ks], al = zl[ks];                                          \
            acc_hh = __builtin_amdgcn_mfma_f32_32x32x16_f16(ah, bh, acc_hh, 0, 0, 0);\
            acc_x1 = __builtin_amdgcn_mfma_f32_32x32x16_f16(ah, bl, acc_x1, 0, 0, 0);\
            acc_x2 = __builtin_amdgcn_mfma_f32_32x32x16_f16(al, bh, acc_x2, 0, 0, 0);\
        }                                                                            \
    }

__global__ __launch_bounds__(NTHREADS, 2)
void vq_main_mfma(const float* __restrict__ z, const char* __restrict__ img,
                  const float* __restrict__ cnorm, int* __restrict__ bests_g,
                  int* __restrict__ counts, float* __restrict__ ploss) {
    __shared__ _Float16 csb[32768];              // 64 KB SINGLE chunk buffer
    __shared__ float cnorm_lds[1024];            // 4 KB (folds never touch vmcnt)
    __shared__ float bs2[BM][2];
    __shared__ int   bc2[BM][2];
    __shared__ float znorm_lds[BM];
    __shared__ float red[NTHREADS];

    const int tid  = threadIdx.x;
    const int lane = tid & 63;
    const int w    = tid >> 6;      // wave 0..7
    const int wr   = w >> 1;        // row-tile 0..3 (32 rows each)
    const int wc   = w & 1;         // col-half of 64-code chunk
    const int l31  = lane & 31;
    const int lh   = lane >> 5;
    const int r0   = blockIdx.x * BM;

    // issue chunk-0 stage early (latency hides under z prologue)
    stage_chunk(img, 0, (char*)csb, tid);

    // ---- z fragments -> registers (f16 hi/lo, MFMA A layout) + row norms ----
    const int zrow = wr * 32 + l31;
    f16x8 zh[16], zl[16];
    {
        const float* zr = z + (size_t)(r0 + zrow) * DIM;
        float zn = 0.f;
#pragma unroll
        for (int gi = 0; gi < 16; ++gi) {
            int g = gi * 2 + lh;                 // granule parity = lh
            float4 v0 = *(const float4*)(zr + g * 8);
            float4 v1 = *(const float4*)(zr + g * 8 + 4);
            float vv[8] = {v0.x, v0.y, v0.z, v0.w, v1.x, v1.y, v1.z, v1.w};
            f16x8 hi, lo;
#pragma unroll
            for (int j = 0; j < 8; ++j) {
                _Float16 h = (_Float16)vv[j];
                hi[j] = h;
                lo[j] = (_Float16)((vv[j] - (float)h) * LO_SCALE);
                zn = fmaf(vv[j], vv[j], zn);
            }
            zh[gi] = hi;
            zl[gi] = lo;
        }
        zn += __shfl_xor(zn, 32, 64);            // combine lh halves
        if (wc == 0 && lh == 0) znorm_lds[zrow] = zn;
    }

    // cnorm -> LDS
    cnorm_lds[tid]       = cnorm[tid];
    cnorm_lds[tid + 512] = cnorm[tid + 512];

    f32x16 acc_hh, acc_x1, acc_x2;
#pragma unroll
    for (int e = 0; e < 16; ++e) { acc_hh[e] = 0.f; acc_x1[e] = 0.f; acc_x2[e] = 0.f; }
    float best_s[16];
    int   best_c[16];
#pragma unroll
    for (int e = 0; e < 16; ++e) { best_s[e] = 3.4e38f; best_c[e] = 0; }

    const int crow = wc * 32 + l31;              // code row within 64-chunk

#pragma unroll 1
    for (int c = 0; c < NCHUNK; ++c) {
        // stage(c) was issued last iteration (or prologue): drain own loads,
        // then barrier -> every wave's stage writes are visible.
        asm volatile("s_waitcnt vmcnt(0)" ::: "memory");
        __builtin_amdgcn_s_barrier();
        asm volatile("" ::: "memory");

        __builtin_amdgcn_s_setprio(1);
        COMPUTE_CHUNK()
        __builtin_amdgcn_s_setprio(0);

        asm volatile("" ::: "memory");
        __builtin_amdgcn_s_barrier();            // all waves done reading csb
        asm volatile("" ::: "memory");

        // refill for chunk c+1 (latency covered by fold + other resident work)
        if (c + 1 < NCHUNK)
            stage_chunk(img, c + 1, (char*)csb, tid);

        // ---- fold chunk c (registers + cnorm_lds only) ----
        {
            int col = c * 64 + crow;
            float cn = cnorm_lds[col];
#pragma unroll
            for (int rg = 0; rg < 16; ++rg) {
                float dot = fmaf(acc_x1[rg] + acc_x2[rg], LO_INV, acc_hh[rg]);
                float s = fmaf(-2.0f, dot, cn);
                bool take = s < best_s[rg];      // strict: earlier (smaller) col wins ties
                best_s[rg] = take ? s : best_s[rg];
                best_c[rg] = take ? col : best_c[rg];
            }
#pragma unroll
            for (int e = 0; e < 16; ++e) { acc_hh[e] = 0.f; acc_x1[e] = 0.f; acc_x2[e] = 0.f; }
        }
    }

    // ---- reduce best over the 32 lanes of each half (codes axis) ----
#pragma unroll
    for (int rg = 0; rg < 16; ++rg) {
        float bsv = best_s[rg];
        int   bcv = best_c[rg];
#pragma unroll
        for (int s = 1; s < 32; s <<= 1) {
            float os = __shfl_xor(bsv, s, 64);
            int   oc = __shfl_xor(bcv, s, 64);
            bool take = (os < bsv) || (os == bsv && oc < bcv);
            bsv = take ? os : bsv;
            bcv = take ? oc : bcv;
        }
        best_s[rg] = bsv;
        best_c[rg] = bcv;
    }
    if (l31 == 0) {
#pragma unroll
        for (int rg = 0; rg < 16; ++rg) {
            int rl = (rg & 3) + 8 * (rg >> 2) + 4 * lh;   // C/D row mapping (m74/m101)
            bs2[wr * 32 + rl][wc] = best_s[rg];
            bc2[wr * 32 + rl][wc] = best_c[rg];
        }
    }
    __syncthreads();

    // ---- combine wc halves, emit bests + per-row loss (score + ||z||^2) ----
    float lsum = 0.f;
    if (tid < BM) {
        float s0 = bs2[tid][0], s1 = bs2[tid][1];
        int   c0 = bc2[tid][0], c1 = bc2[tid][1];
        bool t1 = (s1 < s0) || (s1 == s0 && c1 < c0);
        int   bc = t1 ? c1 : c0;
        float bs = t1 ? s1 : s0;
        bests_g[r0 + tid] = bc;
        atomicAdd(&counts[bc], 1);
        lsum = bs + znorm_lds[tid];              // ||z - c||^2
    }
    red[tid] = lsum;
    __syncthreads();
    for (int s = NTHREADS / 2; s > 0; s >>= 1) {
        if (tid < s) red[tid] += red[tid + s];
        __syncthreads();
    }
    if (tid == 0) ploss[blockIdx.x] = red[0];
}

// ---------------- z_q gather kernel (z + stopgrad(zq - z) == codebook row) ----

__global__ __launch_bounds__(256)
void vq_gather(const float4* __restrict__ cb4, const int* __restrict__ bests,
               float4* __restrict__ out4) {
    int gid = blockIdx.x * blockDim.x + threadIdx.x;   // 0 .. 4194303
    int row = gid >> 6;
    int q   = gid & 63;
    out4[gid] = cb4[(size_t)bests[row] * 64 + q];
}

// ---------------- fallback fp32 kernel (round-1, known-good) ----------------

#define FBM     32
#define FCHUNK  512
#define FDSTAGE 16
#define FCS_PAD 20
#define FNBLOCKS (N_ROWS / FBM)   // 2048

__global__ void cnorm_kernel(const float* __restrict__ cb, float* __restrict__ cnorm) {
    int k = blockIdx.x * blockDim.x + threadIdx.x;
    if (k >= K_CODES) return;
    const float4* row = (const float4*)(cb + (size_t)k * DIM);
    float s = 0.f;
#pragma unroll
    for (int j = 0; j < DIM / 4; ++j) {
        float4 v = row[j];
        s = fmaf(v.x, v.x, s);
        s = fmaf(v.y, v.y, s);
        s = fmaf(v.z, v.z, s);
        s = fmaf(v.w, v.w, s);
    }
    cnorm[k] = s;
}

__global__ __launch_bounds__(256, 2)
void vq_main_fp32(const float* __restrict__ z, const float* __restrict__ cb,
                  const float* __restrict__ cnorm, float* __restrict__ out,
                  int* __restrict__ counts, float* __restrict__ ploss) {
    __shared__ float zs[FBM][DIM];
    __shared__ float cs[FCHUNK][FCS_PAD];
    __shared__ int   bests[FBM];
    __shared__ float red[256];

    const int tid = threadIdx.x;
    const int tx  = tid & 63;
    const int ty  = tid >> 6;
    const int r0  = blockIdx.x * FBM;

    {
        const float4* zg  = (const float4*)(z + (size_t)r0 * DIM);
        float4*       zsv = (float4*)&zs[0][0];
#pragma unroll
        for (int j = 0; j < (FBM * DIM / 4) / 256; ++j)
            zsv[tid + 256 * j] = zg[tid + 256 * j];
    }

    unsigned long long best[8];
#pragma unroll
    for (int i = 0; i < 8; ++i) best[i] = ~0ull;

    for (int cb0 = 0; cb0 < K_CODES; cb0 += FCHUNK) {
        float acc[8][8];
#pragma unroll
        for (int i = 0; i < 8; ++i)
#pragma unroll
            for (int m = 0; m < 8; ++m) acc[i][m] = 0.f;

        for (int sd = 0; sd < DIM / FDSTAGE; ++sd) {
            __syncthreads();
#pragma unroll
            for (int j = 0; j < 8; ++j) {
                int f4i = tid + 256 * j;
                int c   = f4i >> 2;
                int qq  = f4i & 3;
                float4 v = *(const float4*)(cb + (size_t)(cb0 + c) * DIM + sd * FDSTAGE + qq * 4);
                *(float4*)&cs[c][qq * 4] = v;
            }
            __syncthreads();

#pragma unroll
            for (int dd4 = 0; dd4 < FDSTAGE / 4; ++dd4) {
                float4 zv[8], cv[8];
#pragma unroll
                for (int i = 0; i < 8; ++i)
                    zv[i] = *(const float4*)&zs[ty * 8 + i][sd * FDSTAGE + dd4 * 4];
#pragma unroll
                for (int m = 0; m < 8; ++m)
                    cv[m] = *(const float4*)&cs[tx + 64 * m][dd4 * 4];
#pragma unroll
                for (int i = 0; i < 8; ++i)
#pragma unroll
                    for (int m = 0; m < 8; ++m) {
                        float a = acc[i][m];
                        a = fmaf(zv[i].x, cv[m].x, a);
                        a = fmaf(zv[i].y, cv[m].y, a);
                        a = fmaf(zv[i].z, cv[m].z, a);
                        a = fmaf(zv[i].w, cv[m].w, a);
                        acc[i][m] = a;
                    }
            }
        }

#pragma unroll
        for (int m = 0; m < 8; ++m) {
            int   c  = cb0 + tx + 64 * m;
            float cn = cnorm[c];
#pragma unroll
            for (int i = 0; i < 8; ++i) {
                float s = fmaf(-2.f, acc[i][m], cn);
                unsigned u = __float_as_uint(s);
                u = (u & 0x80000000u) ? ~u : (u | 0x80000000u);
                unsigned long long key = ((unsigned long long)u << 32) | (unsigned)c;
                best[i] = key < best[i] ? key : best[i];
            }
        }
    }

#pragma unroll
    for (int i = 0; i < 8; ++i) {
        unsigned long long b = best[i];
#pragma unroll
        for (int s = 1; s < 64; s <<= 1) {
            unsigned long long o = __shfl_xor(b, s, 64);
            b = o < b ? o : b;
        }
        best[i] = b;
    }
    if (tx == 0)
#pragma unroll
        for (int i = 0; i < 8; ++i)
            bests[ty * 8 + i] = (int)(best[i] & 0xFFFFFFFFu);
    __syncthreads();

    const int r  = tid >> 3;
    const int lq = tid & 7;
    const int bidx = bests[r];
    const float4* crow = (const float4*)(cb + (size_t)bidx * DIM);
    const float4* zrow = (const float4*)&zs[r][0];
    float4*       orow = (float4*)(out + (size_t)(r0 + r) * DIM);
    float lsum = 0.f;
#pragma unroll
    for (int j = 0; j < 8; ++j) {
        int qg = lq + j * 8;
        float4 c4 = crow[qg];
        float4 z4 = zrow[qg];
        float4 o;
        float dx = c4.x - z4.x; o.x = z4.x + dx; lsum = fmaf(dx, dx, lsum);
        float dy = c4.y - z4.y; o.y = z4.y + dy; lsum = fmaf(dy, dy, lsum);
        float dz = c4.z - z4.z; o.z = z4.z + dz; lsum = fmaf(dz, dz, lsum);
        float dw = c4.w - z4.w; o.w = z4.w + dw; lsum = fmaf(dw, dw, lsum);
        orow[qg] = o;
    }
    if (tid < FBM) atomicAdd(&counts[bests[tid]], 1);

    red[tid] = lsum;
    __syncthreads();
    for (int s = 128; s > 0; s >>= 1) {
        if (tid < s) red[tid] += red[tid + s];
        __syncthreads();
    }
    if (tid == 0) ploss[blockIdx.x] = red[0];
}

// ---------------- finalize ----------------

__global__ void vq_final(const float* __restrict__ ploss, const int* __restrict__ counts,
                         const int* __restrict__ flg, float* __restrict__ out2, int np) {
    __shared__ float red[1024];
    const int t = threadIdx.x;

    float l = 0.f;
    for (int i = t; i < np; i += 1024) l += ploss[i];
    red[t] = l;
    __syncthreads();
    for (int s = 512; s > 0; s >>= 1) {
        if (t < s) red[t] += red[t + s];
        __syncthreads();
    }
    if (t == 0) {
        float loss = (red[0] / (float)((size_t)N_ROWS * DIM)) * (1.0f + BETA);
        if (flg[0] == 0) loss = 0.f;
        out2[0] = loss;
    }
    __syncthreads();

    float e = (float)counts[t] / (float)N_ROWS;
    red[t] = e * logf(e + 1e-10f);
    __syncthreads();
    for (int s = 512; s > 0; s >>= 1) {
        if (t < s) red[t] += red[t + s];
        __syncthreads();
    }
    if (t == 0) out2[1] = expf(-red[0]);
}

extern "C" void kernel_launch(void* const* d_in, const int* in_sizes, int n_in,
                              void* d_out, int out_size, void* d_ws, size_t ws_size,
                              hipStream_t stream) {
    const float* z   = (const float*)d_in[0];
    const float* cb  = (const float*)d_in[1];
    const int*   flg = (const int*)d_in[2];
    float* out = (float*)d_out;
    float* ws  = (float*)d_ws;

    float* cnorm  = ws;
    int*   counts = (int*)((char*)d_ws + 4096);
    float* ploss  = (float*)((char*)d_ws + 8192);
    int*   bests  = (int*)((char*)d_ws + WS_BESTS_OFF);
    char*  cbimg  = (char*)d_ws + WS_CBIMG_OFF;

    hipMemsetAsync(counts, 0, K_CODES * sizeof(int), stream);

    if (ws_size >= (size_t)WS_NEED) {
        cb_prep<<<128, 256, 0, stream>>>(cb, cbimg, cnorm);
        vq_main_mfma<<<NBLOCKS, NTHREADS, 0, stream>>>(z, cbimg, cnorm, bests, counts, ploss);
        vq_gather<<<(N_ROWS * 64) / 256, 256, 0, stream>>>((const float4*)cb, bests, (float4*)out);
        vq_final<<<1, 1024, 0, stream>>>(ploss, counts, flg, out + (size_t)N_ROWS * DIM, NBLOCKS);
    } else {
        cnorm_kernel<<<K_CODES / 256, 256, 0, stream>>>(cb, cnorm);
        vq_main_fp32<<<FNBLOCKS, 256, 0, stream>>>(z, cb, cnorm, out, counts, ploss);
        vq_final<<<1, 1024, 0, stream>>>(ploss, counts, flg, out + (size_t)N_ROWS * DIM, FNBLOCKS);
    }
}